// Round 1
// baseline (508.209 us; speedup 1.0000x reference)
//
#include <hip/hip_runtime.h>
#include <hip/hip_bf16.h>
#include <stdint.h>

#define DIM   1024
#define ODIM  3072
#define MROWS 32768   // B(8) * N(4096)
#define RANK  8

#define BM 128
#define BN 128
#define BK 32

typedef unsigned short u16;
typedef __attribute__((ext_vector_type(8))) short short8;
typedef __attribute__((ext_vector_type(8))) unsigned short u16x8;
typedef __attribute__((ext_vector_type(4))) float f32x4;

__device__ __forceinline__ u16 f2bf(float f) {
    uint32_t u = __float_as_uint(f);
    u += 0x7fffu + ((u >> 16) & 1u);   // RNE
    return (u16)(u >> 16);
}
__device__ __forceinline__ float bf2f(u16 h) {
    return __uint_as_float(((uint32_t)h) << 16);
}

// async global->LDS, 16B per lane; LDS dest must be wave-uniform base (HW adds lane*16)
__device__ __forceinline__ void gl2lds16(const void* g, void* l) {
    __builtin_amdgcn_global_load_lds(
        (const __attribute__((address_space(1))) void*)(uintptr_t)g,
        (__attribute__((address_space(3))) void*)(uint32_t)(uintptr_t)l,
        16, 0, 0);
}

// ---------------- f32 -> bf16 conversion (vectorized, grid-stride) ----------------
__global__ __launch_bounds__(256) void k_convert(const float* __restrict__ src,
                                                 u16* __restrict__ dst, int n) {
    const int stride = gridDim.x * blockDim.x;
    for (int t = blockIdx.x * blockDim.x + threadIdx.x; t * 8 < n; t += stride) {
        const int i = t * 8;
        float4 a = *reinterpret_cast<const float4*>(src + i);
        float4 b = *reinterpret_cast<const float4*>(src + i + 4);
        u16x8 o;
        o[0] = f2bf(a.x); o[1] = f2bf(a.y); o[2] = f2bf(a.z); o[3] = f2bf(a.w);
        o[4] = f2bf(b.x); o[5] = f2bf(b.y); o[6] = f2bf(b.z); o[7] = f2bf(b.w);
        *reinterpret_cast<u16x8*>(dst + i) = o;
    }
}

// ---------------- xa = x @ A[idx]  (32768 x 8, for q and v) ----------------
// block = 256 thr = 4 waves, handles 32 consecutive rows (one batch; 4096 % 32 == 0)
__global__ __launch_bounds__(256) void k_lora_xa(const u16* __restrict__ Xc,
                                                 const float* __restrict__ Aq_pool,
                                                 const float* __restrict__ Av_pool,
                                                 const int* __restrict__ idx,
                                                 float* __restrict__ xaq,
                                                 float* __restrict__ xav) {
    __shared__ float sA[2][DIM * RANK];            // 2 x 32KB
    const int rowBase = blockIdx.x * 32;
    const int p = idx[rowBase >> 12];
    const float* gAq = Aq_pool + (size_t)p * (DIM * RANK);
    const float* gAv = Av_pool + (size_t)p * (DIM * RANK);
    for (int t = threadIdx.x; t < DIM * RANK / 4; t += 256) {
        reinterpret_cast<float4*>(sA[0])[t] = reinterpret_cast<const float4*>(gAq)[t];
        reinterpret_cast<float4*>(sA[1])[t] = reinterpret_cast<const float4*>(gAv)[t];
    }
    __syncthreads();
    const int wave = threadIdx.x >> 6, lane = threadIdx.x & 63;
    for (int rr = 0; rr < 8; ++rr) {
        const int row = rowBase + wave * 8 + rr;
        const u16* xr = Xc + (size_t)row * DIM;
        float aq[8] = {0,0,0,0,0,0,0,0};
        float av[8] = {0,0,0,0,0,0,0,0};
        #pragma unroll
        for (int ii = 0; ii < 16; ++ii) {
            const int i = ii * 64 + lane;
            const float xv = bf2f(xr[i]);
            float4 qa = reinterpret_cast<const float4*>(&sA[0][i * 8])[0];
            float4 qb = reinterpret_cast<const float4*>(&sA[0][i * 8])[1];
            float4 va = reinterpret_cast<const float4*>(&sA[1][i * 8])[0];
            float4 vb = reinterpret_cast<const float4*>(&sA[1][i * 8])[1];
            aq[0] += xv * qa.x; aq[1] += xv * qa.y; aq[2] += xv * qa.z; aq[3] += xv * qa.w;
            aq[4] += xv * qb.x; aq[5] += xv * qb.y; aq[6] += xv * qb.z; aq[7] += xv * qb.w;
            av[0] += xv * va.x; av[1] += xv * va.y; av[2] += xv * va.z; av[3] += xv * va.w;
            av[4] += xv * vb.x; av[5] += xv * vb.y; av[6] += xv * vb.z; av[7] += xv * vb.w;
        }
        #pragma unroll
        for (int off = 32; off > 0; off >>= 1) {
            #pragma unroll
            for (int r = 0; r < 8; ++r) {
                aq[r] += __shfl_xor(aq[r], off);
                av[r] += __shfl_xor(av[r], off);
            }
        }
        if (lane == 0) {
            #pragma unroll
            for (int r = 0; r < 8; ++r) {
                xaq[(size_t)row * RANK + r] = aq[r];
                xav[(size_t)row * RANK + r] = av[r];
            }
        }
    }
}

// ---------------- main GEMM: out = Xc @ Wc^T + bias (+ fused LoRA) ----------------
// m97 structure: 128x128 tile, BK=32, 4 waves each owning a 64x64 sub-tile,
// global_load_lds(16B) staging, 16x16x32 bf16 MFMA, 2 barriers / K-step.
__global__ __launch_bounds__(256) void k_gemm(const u16* __restrict__ Xc,
                                              const u16* __restrict__ Wc,
                                              const float* __restrict__ bias,
                                              const float* __restrict__ Bq_pool,
                                              const float* __restrict__ Bv_pool,
                                              const float* __restrict__ xaq,
                                              const float* __restrict__ xav,
                                              const int* __restrict__ idx,
                                              float* __restrict__ out) {
    __shared__ u16 sA[BM * BK];   // 8KB
    __shared__ u16 sB[BN * BK];   // 8KB
    const int tid  = threadIdx.x;
    const int lane = tid & 63, wave = tid >> 6;
    const int m0 = blockIdx.x * BM;
    const int n0 = blockIdx.y * BN;
    const int wr = wave >> 1, wc = wave & 1;

    f32x4 acc[4][4] = {};

    // staging: wave w covers 16 rows per issue; lane l -> row w*16 + l/4, k-slot (l&3)*8
    const u16* gA = Xc + (size_t)(m0 + wave * 16 + (lane >> 2)) * DIM + (lane & 3) * 8;
    const u16* gB = Wc + (size_t)(n0 + wave * 16 + (lane >> 2)) * DIM + (lane & 3) * 8;
    u16* lA = sA + wave * 16 * BK;   // wave-uniform LDS base
    u16* lB = sB + wave * 16 * BK;

    // fragment read base: row = wsub*64 + (lane&15), k = (lane>>4)*8 + j  (same kappa for A and B)
    const u16* pa = sA + (wr * 64 + (lane & 15)) * BK + (lane >> 4) * 8;
    const u16* pb = sB + (wc * 64 + (lane & 15)) * BK + (lane >> 4) * 8;

    for (int k0 = 0; k0 < DIM; k0 += BK) {
        gl2lds16(gA + k0,            lA);
        gl2lds16(gA + k0 + 64 * DIM, lA + 64 * BK);
        gl2lds16(gB + k0,            lB);
        gl2lds16(gB + k0 + 64 * DIM, lB + 64 * BK);
        __syncthreads();   // compiler emits vmcnt(0) drain before barrier
        short8 af[4], bf[4];
        #pragma unroll
        for (int i = 0; i < 4; ++i) {
            af[i] = *reinterpret_cast<const short8*>(pa + i * 16 * BK);
            bf[i] = *reinterpret_cast<const short8*>(pb + i * 16 * BK);
        }
        #pragma unroll
        for (int mi = 0; mi < 4; ++mi)
            #pragma unroll
            for (int ni = 0; ni < 4; ++ni)
                acc[mi][ni] = __builtin_amdgcn_mfma_f32_16x16x32_bf16(af[mi], bf[ni],
                                                                      acc[mi][ni], 0, 0, 0);
        __syncthreads();
    }

    // ---------------- epilogue: bias + LoRA + store ----------------
    const int p = idx[m0 >> 12];                 // 4096 rows per batch, BM=128 divides it
    const float* Bmat = nullptr;
    const float* xa   = nullptr;
    if (n0 < DIM)           { Bmat = Bq_pool + (size_t)p * (RANK * DIM); xa = xaq; }
    else if (n0 >= 2 * DIM) { Bmat = Bv_pool + (size_t)p * (RANK * DIM); xa = xav; }

    const int cn = wc * 64 + (lane & 15);        // col offset within block
    const int slab = n0 % DIM;                   // col offset within the 1024-wide lora slab
    float bcol[4];
    float bq[4][8];
    #pragma unroll
    for (int ni = 0; ni < 4; ++ni) {
        bcol[ni] = bias[n0 + cn + ni * 16];
        if (Bmat) {
            #pragma unroll
            for (int r = 0; r < 8; ++r)
                bq[ni][r] = Bmat[r * DIM + slab + cn + ni * 16];
        }
    }
    const int rbase = m0 + wr * 64 + (lane >> 4) * 4;   // C/D: col=lane&15, row=(lane>>4)*4+v (m89)
    #pragma unroll
    for (int mi = 0; mi < 4; ++mi) {
        float xr[4][8];
        if (Bmat) {
            #pragma unroll
            for (int v = 0; v < 4; ++v) {
                const float4* q = reinterpret_cast<const float4*>(xa + (size_t)(rbase + mi * 16 + v) * RANK);
                float4 x0 = q[0], x1 = q[1];
                xr[v][0] = x0.x; xr[v][1] = x0.y; xr[v][2] = x0.z; xr[v][3] = x0.w;
                xr[v][4] = x1.x; xr[v][5] = x1.y; xr[v][6] = x1.z; xr[v][7] = x1.w;
            }
        }
        #pragma unroll
        for (int ni = 0; ni < 4; ++ni) {
            #pragma unroll
            for (int v = 0; v < 4; ++v) {
                float val = acc[mi][ni][v] + bcol[ni];
                if (Bmat) {
                    float s = 0.f;
                    #pragma unroll
                    for (int r = 0; r < 8; ++r) s += xr[v][r] * bq[ni][r];
                    val += s;   // SCALE = 1.0
                }
                const size_t row = (size_t)(rbase + mi * 16 + v);
                out[row * ODIM + (size_t)(n0 + cn + ni * 16)] = val;
            }
        }
    }
}

extern "C" void kernel_launch(void* const* d_in, const int* in_sizes, int n_in,
                              void* d_out, int out_size, void* d_ws, size_t ws_size,
                              hipStream_t stream) {
    const float* x      = (const float*)d_in[0];
    const float* weight = (const float*)d_in[1];
    const float* bias   = (const float*)d_in[2];
    const float* Bq     = (const float*)d_in[4];
    const float* Aq     = (const float*)d_in[3];
    const float* Av     = (const float*)d_in[5];
    const float* Bv     = (const float*)d_in[6];
    const int*   idx    = (const int*)d_in[7];
    float* out = (float*)d_out;

    // workspace layout: Xc(64MB) | Wc(6MB) | xaq(1MB) | xav(1MB)  = 72MB
    u16*  Xc  = (u16*)d_ws;
    u16*  Wc  = Xc + (size_t)MROWS * DIM;
    float* xaq = (float*)(Wc + (size_t)ODIM * DIM);
    float* xav = xaq + (size_t)MROWS * RANK;

    k_convert<<<2048, 256, 0, stream>>>(x, Xc, MROWS * DIM);
    k_convert<<<1536, 256, 0, stream>>>(weight, Wc, ODIM * DIM);
    k_lora_xa<<<MROWS / 32, 256, 0, stream>>>(Xc, Aq, Av, idx, xaq, xav);
    dim3 grid(MROWS / BM, ODIM / BN);
    k_gemm<<<grid, 256, 0, stream>>>(Xc, Wc, bias, Bq, Bv, xaq, xav, idx, out);
}

// Round 2
// 397.859 us; speedup vs baseline: 1.2774x; 1.2774x over previous
//
#include <hip/hip_runtime.h>
#include <hip/hip_bf16.h>
#include <stdint.h>

#define DIM   1024
#define ODIM  3072
#define MROWS 32768   // B(8) * N(4096)
#define RANK  8
#define NT    16      // K tiles of 64

typedef unsigned short u16;
typedef __attribute__((ext_vector_type(8))) short short8;
typedef __attribute__((ext_vector_type(8))) unsigned short u16x8;
typedef __attribute__((ext_vector_type(4))) float f32x4;

__device__ __forceinline__ u16 f2bf(float f) {
    uint32_t u = __float_as_uint(f);
    u += 0x7fffu + ((u >> 16) & 1u);   // RNE
    return (u16)(u >> 16);
}
__device__ __forceinline__ float bf2f(u16 h) {
    return __uint_as_float(((uint32_t)h) << 16);
}

// async global->LDS, 16B/lane; LDS dest is wave-uniform base + lane*16 (HW)
__device__ __forceinline__ void gl2lds16(const void* g, void* l) {
    __builtin_amdgcn_global_load_lds(
        (const __attribute__((address_space(1))) void*)(uintptr_t)g,
        (__attribute__((address_space(3))) void*)(uint32_t)(uintptr_t)l,
        16, 0, 0);
}

#define BAR() do { asm volatile("" ::: "memory"); __builtin_amdgcn_s_barrier(); asm volatile("" ::: "memory"); } while (0)
#define WAITV(n) asm volatile("s_waitcnt vmcnt(" #n ")" ::: "memory")

// ---------------- f32 -> bf16 conversion ----------------
__global__ __launch_bounds__(256) void k_convert(const float* __restrict__ src,
                                                 u16* __restrict__ dst, int n) {
    const int stride = gridDim.x * blockDim.x;
    for (int t = blockIdx.x * blockDim.x + threadIdx.x; t * 8 < n; t += stride) {
        const int i = t * 8;
        float4 a = *reinterpret_cast<const float4*>(src + i);
        float4 b = *reinterpret_cast<const float4*>(src + i + 4);
        u16x8 o;
        o[0] = f2bf(a.x); o[1] = f2bf(a.y); o[2] = f2bf(a.z); o[3] = f2bf(a.w);
        o[4] = f2bf(b.x); o[5] = f2bf(b.y); o[6] = f2bf(b.z); o[7] = f2bf(b.w);
        *reinterpret_cast<u16x8*>(dst + i) = o;
    }
}

// ---------------- xa = x @ A[idx]  (32768 x 8, q and v) ----------------
__global__ __launch_bounds__(256) void k_lora_xa(const u16* __restrict__ Xc,
                                                 const float* __restrict__ Aq_pool,
                                                 const float* __restrict__ Av_pool,
                                                 const int* __restrict__ idx,
                                                 float* __restrict__ xaq,
                                                 float* __restrict__ xav) {
    __shared__ float sA[2][DIM * RANK];
    const int rowBase = blockIdx.x * 32;
    const int p = idx[rowBase >> 12];
    const float* gAq = Aq_pool + (size_t)p * (DIM * RANK);
    const float* gAv = Av_pool + (size_t)p * (DIM * RANK);
    for (int t = threadIdx.x; t < DIM * RANK / 4; t += 256) {
        reinterpret_cast<float4*>(sA[0])[t] = reinterpret_cast<const float4*>(gAq)[t];
        reinterpret_cast<float4*>(sA[1])[t] = reinterpret_cast<const float4*>(gAv)[t];
    }
    __syncthreads();
    const int wave = threadIdx.x >> 6, lane = threadIdx.x & 63;
    for (int rr = 0; rr < 8; ++rr) {
        const int row = rowBase + wave * 8 + rr;
        const u16* xr = Xc + (size_t)row * DIM;
        float aq[8] = {0,0,0,0,0,0,0,0};
        float av[8] = {0,0,0,0,0,0,0,0};
        #pragma unroll
        for (int ii = 0; ii < 16; ++ii) {
            const int i = ii * 64 + lane;
            const float xv = bf2f(xr[i]);
            float4 qa = reinterpret_cast<const float4*>(&sA[0][i * 8])[0];
            float4 qb = reinterpret_cast<const float4*>(&sA[0][i * 8])[1];
            float4 va = reinterpret_cast<const float4*>(&sA[1][i * 8])[0];
            float4 vb = reinterpret_cast<const float4*>(&sA[1][i * 8])[1];
            aq[0] += xv * qa.x; aq[1] += xv * qa.y; aq[2] += xv * qa.z; aq[3] += xv * qa.w;
            aq[4] += xv * qb.x; aq[5] += xv * qb.y; aq[6] += xv * qb.z; aq[7] += xv * qb.w;
            av[0] += xv * va.x; av[1] += xv * va.y; av[2] += xv * va.z; av[3] += xv * va.w;
            av[4] += xv * vb.x; av[5] += xv * vb.y; av[6] += xv * vb.z; av[7] += xv * vb.w;
        }
        #pragma unroll
        for (int off = 32; off > 0; off >>= 1) {
            #pragma unroll
            for (int r = 0; r < 8; ++r) {
                aq[r] += __shfl_xor(aq[r], off);
                av[r] += __shfl_xor(av[r], off);
            }
        }
        if (lane == 0) {
            #pragma unroll
            for (int r = 0; r < 8; ++r) {
                xaq[(size_t)row * RANK + r] = aq[r];
                xav[(size_t)row * RANK + r] = av[r];
            }
        }
    }
}

// ---------------- 256x256 8-wave double-buffered GEMM ----------------
// LDS per buffer: A 256x64 bf16 (32KB) + B 256x64 (32KB); 2 buffers = 128KB.
// Swizzle (T2): u16 row-major [r][64], 16B group g stored at g ^ (r&7).
// Write side: pre-swizzled GLOBAL source + linear gl2lds dest (rule #21).
// Schedule (T3/T4): stage tile t+1 (8 loads) -> vmcnt(8) -> barrier ->
//                   64 MFMA from tile t (no intra-tile barrier) -> barrier.

__device__ __forceinline__ void stage_tile(const u16* __restrict__ Xc,
                                           const u16* __restrict__ Wc,
                                           int m0, int n0, int tk,
                                           u16* sbuf, int wave, int lane) {
    const int lrow = lane >> 3;                 // 0..7 row within 8-row stripe
    const int g    = (lane & 7) ^ lrow;         // pre-swizzled 16B group
    const u16* gA = Xc + (size_t)(m0 + wave * 8 + lrow) * DIM + tk * 64 + g * 8;
    const u16* gB = Wc + (size_t)(n0 + wave * 8 + lrow) * DIM + tk * 64 + g * 8;
    u16* lA = sbuf + (wave * 8) * 64;           // wave-uniform LDS bases
    u16* lB = sbuf + 16384 + (wave * 8) * 64;
    #pragma unroll
    for (int c = 0; c < 4; ++c) {
        gl2lds16(gA + (size_t)(c * 64) * DIM, lA + c * 64 * 64);
        gl2lds16(gB + (size_t)(c * 64) * DIM, lB + c * 64 * 64);
    }
}

__device__ __forceinline__ void compute_tile(const u16* __restrict__ sAb,
                                             const u16* __restrict__ sBb,
                                             int aoff, int boff, int kx0, int kx1,
                                             f32x4 (&acc)[8][4]) {
    short8 a[4], b[4];
    __builtin_amdgcn_s_setprio(1);
    #pragma unroll
    for (int ks = 0; ks < 2; ++ks) {
        const int kx = ks ? kx1 : kx0;
        #pragma unroll
        for (int ni = 0; ni < 4; ++ni)
            b[ni] = *reinterpret_cast<const short8*>(sBb + boff + kx + ni * 1024);
        #pragma unroll
        for (int mg = 0; mg < 2; ++mg) {
            #pragma unroll
            for (int i = 0; i < 4; ++i)
                a[i] = *reinterpret_cast<const short8*>(sAb + aoff + kx + (mg * 4 + i) * 1024);
            #pragma unroll
            for (int i = 0; i < 4; ++i)
                #pragma unroll
                for (int ni = 0; ni < 4; ++ni)
                    acc[mg * 4 + i][ni] = __builtin_amdgcn_mfma_f32_16x16x32_bf16(
                        a[i], b[ni], acc[mg * 4 + i][ni], 0, 0, 0);
        }
    }
    __builtin_amdgcn_s_setprio(0);
}

__global__ __launch_bounds__(512, 2) void k_gemm(const u16* __restrict__ Xc,
                                                 const u16* __restrict__ Wc,
                                                 const float* __restrict__ bias,
                                                 const float* __restrict__ Bq_pool,
                                                 const float* __restrict__ Bv_pool,
                                                 const float* __restrict__ xaq,
                                                 const float* __restrict__ xav,
                                                 const int* __restrict__ idx,
                                                 float* __restrict__ out) {
    extern __shared__ u16 lds[];               // 2 * 32768 u16 = 128 KiB
    u16* s0 = lds;
    u16* s1 = lds + 32768;

    const int tid  = threadIdx.x;
    const int lane = tid & 63, wave = tid >> 6;
    const int wr = wave >> 2, wc = wave & 3;   // 2M x 4N wave grid

    // bijective XCD swizzle (nwg=1536, 1536%8==0) then n-fastest decode
    const int orig = blockIdx.x;
    const int wg   = (orig & 7) * 192 + (orig >> 3);
    const int bn   = wg % 12;
    const int bm   = wg / 12;
    const int m0 = bm * 256, n0 = bn * 256;

    const int aoff = (wr * 128 + (lane & 15)) * 64;
    const int boff = (wc * 64  + (lane & 15)) * 64;
    const int kx0  = (((lane >> 4)    ) ^ (lane & 7)) * 8;
    const int kx1  = (((lane >> 4) + 4) ^ (lane & 7)) * 8;

    f32x4 acc[8][4] = {};

    stage_tile(Xc, Wc, m0, n0, 0, s0, wave, lane);
    #pragma unroll 1
    for (int it = 0; it < 7; ++it) {
        stage_tile(Xc, Wc, m0, n0, 2 * it + 1, s1, wave, lane);
        WAITV(8); BAR();
        compute_tile(s0, s0 + 16384, aoff, boff, kx0, kx1, acc);
        BAR();
        stage_tile(Xc, Wc, m0, n0, 2 * it + 2, s0, wave, lane);
        WAITV(8); BAR();
        compute_tile(s1, s1 + 16384, aoff, boff, kx0, kx1, acc);
        BAR();
    }
    stage_tile(Xc, Wc, m0, n0, 15, s1, wave, lane);
    WAITV(8); BAR();
    compute_tile(s0, s0 + 16384, aoff, boff, kx0, kx1, acc);
    BAR();
    WAITV(0); BAR();
    compute_tile(s1, s1 + 16384, aoff, boff, kx0, kx1, acc);

    // ---------------- epilogue: bias + LoRA + store ----------------
    const int p = idx[m0 >> 12];
    const float* Bmat = nullptr;
    const float* xa   = nullptr;
    if (n0 < DIM)           { Bmat = Bq_pool + (size_t)p * (RANK * DIM); xa = xaq; }
    else if (n0 >= 2 * DIM) { Bmat = Bv_pool + (size_t)p * (RANK * DIM); xa = xav; }

    const int cn   = wc * 64 + (lane & 15);
    const int slab = n0 % DIM;
    float bcol[4];
    float bq[4][8];
    #pragma unroll
    for (int ni = 0; ni < 4; ++ni) {
        bcol[ni] = bias[n0 + cn + ni * 16];
        if (Bmat) {
            #pragma unroll
            for (int r = 0; r < 8; ++r)
                bq[ni][r] = Bmat[r * DIM + slab + cn + ni * 16];
        }
    }
    const int rbase = m0 + wr * 128 + (lane >> 4) * 4;   // C/D: col=lane&15, row=(lane>>4)*4+v
    #pragma unroll
    for (int mi = 0; mi < 8; ++mi) {
        #pragma unroll
        for (int v = 0; v < 4; ++v) {
            const size_t row = (size_t)(rbase + mi * 16 + v);
            float xr[8];
            if (Bmat) {
                const float4* q = reinterpret_cast<const float4*>(xa + row * RANK);
                float4 x0 = q[0], x1 = q[1];
                xr[0] = x0.x; xr[1] = x0.y; xr[2] = x0.z; xr[3] = x0.w;
                xr[4] = x1.x; xr[5] = x1.y; xr[6] = x1.z; xr[7] = x1.w;
            }
            #pragma unroll
            for (int ni = 0; ni < 4; ++ni) {
                float val = acc[mi][ni][v] + bcol[ni];
                if (Bmat) {
                    float s = 0.f;
                    #pragma unroll
                    for (int r = 0; r < 8; ++r) s += xr[r] * bq[ni][r];
                    val += s;   // SCALE = 1.0
                }
                out[row * ODIM + (size_t)(n0 + cn + ni * 16)] = val;
            }
        }
    }
}

extern "C" void kernel_launch(void* const* d_in, const int* in_sizes, int n_in,
                              void* d_out, int out_size, void* d_ws, size_t ws_size,
                              hipStream_t stream) {
    const float* x      = (const float*)d_in[0];
    const float* weight = (const float*)d_in[1];
    const float* bias   = (const float*)d_in[2];
    const float* Aq     = (const float*)d_in[3];
    const float* Bq     = (const float*)d_in[4];
    const float* Av     = (const float*)d_in[5];
    const float* Bv     = (const float*)d_in[6];
    const int*   idx    = (const int*)d_in[7];
    float* out = (float*)d_out;

    // workspace: Xc(64MB) | Wc(6MB) | xaq(1MB) | xav(1MB)
    u16*  Xc  = (u16*)d_ws;
    u16*  Wc  = Xc + (size_t)MROWS * DIM;
    float* xaq = (float*)(Wc + (size_t)ODIM * DIM);
    float* xav = xaq + (size_t)MROWS * RANK;

    hipFuncSetAttribute(reinterpret_cast<const void*>(k_gemm),
                        hipFuncAttributeMaxDynamicSharedMemorySize, 131072);

    k_convert<<<2048, 256, 0, stream>>>(x, Xc, MROWS * DIM);
    k_convert<<<1536, 256, 0, stream>>>(weight, Wc, ODIM * DIM);
    k_lora_xa<<<MROWS / 32, 256, 0, stream>>>(Xc, Aq, Av, idx, xaq, xav);
    k_gemm<<<1536, 512, 131072, stream>>>(Xc, Wc, bias, Bq, Bv, xaq, xav, idx, out);
}